// Round 10
// baseline (844.182 us; speedup 1.0000x reference)
//
#include <hip/hip_runtime.h>
#include <hip/hip_bf16.h>

typedef __bf16 bf16x8 __attribute__((ext_vector_type(8)));
typedef float f32x4 __attribute__((ext_vector_type(4)));

__device__ __forceinline__ unsigned short f2bf(float x) {
  union { float f; unsigned int u; } v; v.f = x;
  unsigned int r = (v.u + 0x7FFFu + ((v.u >> 16) & 1u)) >> 16;
  return (unsigned short)r;
}
__device__ __forceinline__ float bf2f(unsigned short u) {
  union { unsigned int u; float f; } v; v.u = ((unsigned int)u) << 16;
  return v.f;
}

// feats [N][16] f32 -> [N+1][32] bf16 (upper 16 cols and row N stay zero via memset)
__global__ void cvt_feats_kernel(const float* __restrict__ f, unsigned short* __restrict__ fb, int n16) {
  int t = blockIdx.x * 256 + threadIdx.x;
  if (t >= n16) return;
  int i = t >> 4, j = t & 15;
  fb[(size_t)i * 32 + j] = f2bf(f[t]);
}

// Pack W[k][CI][CO] f32 into MFMA B-fragment order:
// Wp[(((k*NT+nt)*KK+kk)*64 + l)*8 + j] = bf16(W[k][kk*32 + (l>>4)*8 + j][nt*16 + (l&15)]), 0 if kg>=CI
__global__ void pack_w_kernel(const float* __restrict__ W, unsigned short* __restrict__ Wp,
                              int CI, int CO, int NT, int KK) {
  int t = blockIdx.x * 256 + threadIdx.x;
  int total = 27 * NT * KK * 512;
  if (t >= total) return;
  int j = t & 7, l = (t >> 3) & 63;
  int g = t >> 9;
  int kk = g % KK; g /= KK;
  int nt = g % NT; int k = g / NT;
  int kg = kk * 32 + ((l >> 4) * 8) + j;
  int c = nt * 16 + (l & 15);
  float v = (kg < CI) ? W[((size_t)k * CI + kg) * CO + c] : 0.0f;
  Wp[t] = f2bf(v);
}

// tab[k][o] = input index (scatter from pair lists; unique per (k,o) by construction)
__global__ void build_table_kernel(const int* __restrict__ pin, const int* __restrict__ pout,
                                   int P, int maxo, int* __restrict__ tab,
                                   const int* __restrict__ n_ptr, int n_cap) {
  int p = blockIdx.x * 256 + threadIdx.x;
  if (p >= P) return;
  int k = blockIdx.y;
  int n = n_cap;
  if (n_ptr) { int nv = n_ptr[0]; if (nv < n) n = nv; }
  size_t e = (size_t)k * P + p;
  int o = pout[e];
  if (o < n) tab[(size_t)k * maxo + o] = pin[e];
}

// Per-lane tab loads for this wave's two 16-row groups (predicated, no shfl).
#define LDTAB(KC_, T0, T1) do {                                                  \
    int _kc = (KC_) > 26 ? 26 : (KC_);                                           \
    T0 = ok0 ? tab[(size_t)_kc * maxo + row0] : -1;                              \
    T1 = ok1 ? tab[(size_t)_kc * maxo + row1] : -1;                              \
  } while (0)

// Gather A fragments into AB from tab values T0/T1; sets D (SKIP only).
#define ISSUE_A(AB, T0, T1, D) do {                                              \
    if (SKIP) D = (__ballot((T0) >= 0 || (T1) >= 0) != 0ull);                    \
    const unsigned short* _s0 = Xb + (size_t)((T0) < 0 ? zrow : (T0)) * ROWS + lg * 8; \
    _Pragma("unroll") for (int kk = 0; kk < KK; ++kk)                            \
      AB[0][kk] = *reinterpret_cast<const bf16x8*>(_s0 + kk * 32);               \
    const unsigned short* _s1 = Xb + (size_t)((T1) < 0 ? zrow : (T1)) * ROWS + lg * 8; \
    _Pragma("unroll") for (int kk = 0; kk < KK; ++kk)                            \
      AB[1][kk] = *reinterpret_cast<const bf16x8*>(_s1 + kk * 32);               \
  } while (0)

// Cooperative LDS staging of B(K) into BUF (linear copy; wave w stages PER chunks)
#define STAGE_B(K, BUF) do {                                                     \
    if ((K) <= 26) {                                                             \
      size_t _kb = (size_t)(K) * (size_t)(KK * NT * 1024);                       \
      _Pragma("unroll") for (int _j = 0; _j < PER; ++_j) {                       \
        int _c = w * PER + _j;                                                   \
        const unsigned char* _gp = WpB + _kb + (size_t)_c * 1024 + (size_t)l * 16; \
        __builtin_amdgcn_global_load_lds(                                        \
            (const __attribute__((address_space(1))) void*)_gp,                  \
            (__attribute__((address_space(3))) void*)(&BUF[_c * 1024]), 16, 0, 0); \
      }                                                                          \
    }                                                                            \
  } while (0)

// ds_read B(k) fragments + MFMA on buffer AB (skipped per-wave if sparse+empty)
#define STEP_CORE(BCUR, AB, D) do {                                              \
    if (!SKIP || (D)) {                                                          \
      _Pragma("unroll") for (int kk = 0; kk < KK; ++kk)                          \
        _Pragma("unroll") for (int nt = 0; nt < NT; ++nt) {                      \
          bf16x8 b = *reinterpret_cast<const bf16x8*>(&(BCUR)[(nt * KK + kk) * 1024 + l * 16]); \
          acc[0][nt] = __builtin_amdgcn_mfma_f32_16x16x32_bf16(AB[0][kk], b, acc[0][nt], 0, 0, 0); \
          acc[1][nt] = __builtin_amdgcn_mfma_f32_16x16x32_bf16(AB[1][kk], b, acc[1][nt], 0, 0, 0); \
        }                                                                        \
    }                                                                            \
  } while (0)

// Block = 4 waves x 32 rows, lockstep over k=0..26. B(k) staged in LDS
// (3-buffer rotation, one barrier/step, staged 2 steps ahead via
// global_load_lds); A per-wave ping-pong regs 2 ahead; tab 4 ahead.
// launch_bounds(256,6): R8 was artificially capped at 3 waves/SIMD (occ 34%);
// VGPR 48 / LDS 24KB allow 6 -> double TLP to hide gather latency.
template<int KK, int NT, bool SKIP>
__global__ __launch_bounds__(256, 6) void conv_mfma_kernel(
    const unsigned short* __restrict__ Xb, const unsigned short* __restrict__ Wp,
    const int* __restrict__ tab, int maxo, int zrow,
    const int* __restrict__ n_ptr, int n_cap,
    unsigned short* __restrict__ outb, float* __restrict__ outf) {
  const int CO = NT * 16;
  const int ROWS = KK * 32;         // shorts per X row
  constexpr int PER = (KK * NT) / 4;  // staging chunks (1KB) per wave
  constexpr int SZ = KK * NT * 1024;  // bytes per LDS B buffer

  __shared__ __align__(16) unsigned char Blds[3][SZ];

  int bid = blockIdx.x;
  { // bijective XCD-aware swizzle (m204)
    int nwg = gridDim.x;
    int q = nwg >> 3, r = nwg & 7;
    int xcd = bid & 7, orig = bid >> 3;
    bid = (xcd < r ? xcd * (q + 1) : r * (q + 1) + (xcd - r) * q) + orig;
  }

  int w = threadIdx.x >> 6, l = threadIdx.x & 63;
  int n_rows = n_cap;
  if (n_ptr) { int nv = n_ptr[0]; if (nv < n_rows) n_rows = nv; }
  if (bid * 128 >= n_rows) return;   // block-uniform exit (before any barrier)
  int lr = l & 15, lg = l >> 4;
  int wbase = bid * 128 + w * 32;
  int row0 = wbase + lr, row1 = wbase + 16 + lr;
  bool ok0 = row0 < n_rows, ok1 = row1 < n_rows;

  const unsigned char* WpB = (const unsigned char*)Wp;

  f32x4 acc[2][NT] = {};
  bf16x8 a0[2][KK], a1[2][KK];
  int tE0, tE1, tO0, tO1;
  bool dE = true, dO = true;

  // ---- prologue ----
  LDTAB(0, tE0, tE1);
  LDTAB(1, tO0, tO1);
  STAGE_B(0, Blds[0]);
  STAGE_B(1, Blds[1]);
  ISSUE_A(a0, tE0, tE1, dE);       // A(0), dE for step 0
  ISSUE_A(a1, tO0, tO1, dO);       // A(1), dO for step 1
  LDTAB(2, tE0, tE1);
  LDTAB(3, tO0, tO1);
  __syncthreads();                 // B(0),B(1),A(0),A(1),tabs all complete

  int cur = 0;                     // buffer holding B(k) at loop head (== k%3)
#pragma unroll 1
  for (int k = 0; k < 26; k += 2) {
    // ---- step k (even) ----
    STAGE_B(k + 2, Blds[(cur + 2) % 3]);
    STEP_CORE(Blds[cur], a0, dE);           // consumes A(k), B(k)
    ISSUE_A(a0, tE0, tE1, dE);              // A(k+2), dE for step k+2
    LDTAB(k + 4, tE0, tE1);
    __syncthreads();
    // ---- step k+1 (odd) ----
    STAGE_B(k + 3, Blds[cur]);              // (cur+3)%3 == cur
    STEP_CORE(Blds[(cur + 1) % 3], a1, dO); // consumes A(k+1), B(k+1)
    ISSUE_A(a1, tO0, tO1, dO);              // A(k+3), dO for step k+3
    LDTAB(k + 5, tO0, tO1);
    __syncthreads();
    cur = (cur + 2) % 3;
  }
  // ---- tail: step 26 (B(26) in Blds[26%3=2] == Blds[cur]) ----
  STEP_CORE(Blds[cur], a0, dE);

#pragma unroll
  for (int mt = 0; mt < 2; ++mt) {
    int r0 = wbase + mt * 16 + lg * 4;
#pragma unroll
    for (int rr = 0; rr < 4; ++rr) {
      int row = r0 + rr;
      if (row < n_rows) {
#pragma unroll
        for (int nt = 0; nt < NT; ++nt) {
          size_t off = (size_t)row * CO + nt * 16 + lr;
          if (outf) outf[off] = acc[mt][nt][rr];
          else outb[off] = f2bf(acc[mt][nt][rr]);
        }
      }
    }
  }
}

__global__ void bn_stats_kernel(const unsigned short* __restrict__ xb,
                                const int* __restrict__ n_ptr, int n_cap,
                                float* __restrict__ stats) {
  int c = threadIdx.x & 63, q = threadIdx.x >> 6;
  int n = n_ptr[0]; if (n > n_cap) n = n_cap;
  float s = 0.f, ss = 0.f;
  for (int r = blockIdx.x * 4 + q; r < n; r += gridDim.x * 4) {
    float v = bf2f(xb[(size_t)r * 64 + c]);
    s += v; ss += v * v;
  }
  __shared__ float ls[8][64];
  ls[q][c] = s; ls[4 + q][c] = ss;
  __syncthreads();
  if (q == 0) {
    s = ls[0][c] + ls[1][c] + ls[2][c] + ls[3][c];
    ss = ls[4][c] + ls[5][c] + ls[6][c] + ls[7][c];
    atomicAdd(&stats[c], s);
    atomicAdd(&stats[64 + c], ss);
  }
}

__global__ void bn_apply_kernel(unsigned short* __restrict__ xb,
                                const int* __restrict__ n_ptr, int n_cap,
                                const float* __restrict__ stats,
                                const float* __restrict__ gamma, const float* __restrict__ beta) {
  int c = threadIdx.x & 63, q = threadIdx.x >> 6;
  int n = n_ptr[0]; if (n > n_cap) n = n_cap;
  float inv_n = 1.f / (float)n;
  float m = stats[c] * inv_n;
  float var = stats[64 + c] * inv_n - m * m;
  float sc = gamma[c] * rsqrtf(var + 1e-5f);
  float sh = beta[c] - m * sc;
  for (int r = blockIdx.x * 4 + q; r < n; r += gridDim.x * 4) {
    size_t off = (size_t)r * 64 + c;
    float v = bf2f(xb[off]) * sc + sh;
    xb[off] = f2bf(v > 0.f ? v : 0.f);
  }
}

extern "C" void kernel_launch(void* const* d_in, const int* in_sizes, int n_in,
                              void* d_out, int out_size, void* d_ws, size_t ws_size,
                              hipStream_t stream) {
  const float* feats  = (const float*)d_in[0];
  const float* W1     = (const float*)d_in[1];
  const float* g1     = (const float*)d_in[2];
  const float* b1     = (const float*)d_in[3];
  const float* W2     = (const float*)d_in[4];
  const float* g2     = (const float*)d_in[5];
  const float* b2     = (const float*)d_in[6];
  const float* W3     = (const float*)d_in[7];
  const int* p1_in    = (const int*)d_in[8];
  const int* p1_out   = (const int*)d_in[9];
  const int* p2_in    = (const int*)d_in[10];
  const int* p2_out   = (const int*)d_in[11];
  const int* d_n1     = (const int*)d_in[12];
  float* out = (float*)d_out;

  const int N  = in_sizes[0] / 16;     // 200000
  const int P1 = in_sizes[8] / 27;
  const int P2 = in_sizes[10] / 27;
  long KP1 = in_sizes[8];
  int n1b = (int)(KP1 < 980100 ? KP1 : 980100);   // n1 <= min(#pairs1, out-grid size)
  int maxo = n1b > N ? n1b : N;

  char* p = (char*)d_ws;
  auto alloc = [&](size_t bytes) -> char* {
    char* r = p; p += (bytes + 255) & ~(size_t)255; return r;
  };
  unsigned short* featsb = (unsigned short*)alloc((size_t)(N + 1) * 32 * 2);
  unsigned short* x1b    = (unsigned short*)alloc((size_t)(n1b + 1) * 64 * 2);
  unsigned short* x2b    = (unsigned short*)alloc((size_t)(n1b + 1) * 64 * 2);
  unsigned short* W1p    = (unsigned short*)alloc((size_t)27 * 4 * 1 * 512 * 2);
  unsigned short* W2p    = (unsigned short*)alloc((size_t)27 * 4 * 2 * 512 * 2);
  unsigned short* W3p    = (unsigned short*)alloc((size_t)27 * 2 * 2 * 512 * 2);
  int*   tab   = (int*)alloc((size_t)maxo * 27 * 4);
  float* stats = (float*)alloc(256 * 4);
  if ((size_t)(p - (char*)d_ws) > ws_size) return;  // workspace insufficient -> fail visibly

  // zero-init: padded feats buffer, the two zero-rows, BN stats
  hipMemsetAsync(featsb, 0, (size_t)(N + 1) * 32 * 2, stream);
  hipMemsetAsync(x1b + (size_t)n1b * 64, 0, 64 * 2, stream);
  hipMemsetAsync(x2b + (size_t)n1b * 64, 0, 64 * 2, stream);
  hipMemsetAsync(stats, 0, 256 * 4, stream);

  cvt_feats_kernel<<<(N * 16 + 255) / 256, 256, 0, stream>>>(feats, featsb, N * 16);
  pack_w_kernel<<<(27 * 4 * 1 * 512 + 255) / 256, 256, 0, stream>>>(W1, W1p, 16, 64, 4, 1);
  pack_w_kernel<<<(27 * 4 * 2 * 512 + 255) / 256, 256, 0, stream>>>(W2, W2p, 64, 64, 4, 2);
  pack_w_kernel<<<(27 * 2 * 2 * 512 + 255) / 256, 256, 0, stream>>>(W3, W3p, 64, 32, 2, 2);

  // ---- stage 1: SparseConv3d 16->64 (sparse tab -> SKIP=true) ----
  hipMemsetAsync(tab, 0xFF, (size_t)n1b * 27 * 4, stream);
  build_table_kernel<<<dim3((P1 + 255) / 256, 27), 256, 0, stream>>>(
      p1_in, p1_out, P1, n1b, tab, d_n1, n1b);
  conv_mfma_kernel<1, 4, true><<<(n1b + 127) / 128, 256, 0, stream>>>(
      featsb, W1p, tab, n1b, N, d_n1, n1b, x1b, nullptr);
  bn_stats_kernel<<<1024, 256, 0, stream>>>(x1b, d_n1, n1b, stats);
  bn_apply_kernel<<<2048, 256, 0, stream>>>(x1b, d_n1, n1b, stats, g1, b1);

  // ---- stage 2: SubMConv3d 64->64 (dense tab -> SKIP=false) ----
  hipMemsetAsync(tab, 0xFF, (size_t)n1b * 27 * 4, stream);
  build_table_kernel<<<dim3((P2 + 255) / 256, 27), 256, 0, stream>>>(
      p2_in, p2_out, P2, n1b, tab, d_n1, n1b);
  conv_mfma_kernel<2, 4, false><<<(n1b + 127) / 128, 256, 0, stream>>>(
      x1b, W2p, tab, n1b, n1b, d_n1, n1b, x2b, nullptr);
  bn_stats_kernel<<<1024, 256, 0, stream>>>(x2b, d_n1, n1b, stats + 128);
  bn_apply_kernel<<<2048, 256, 0, stream>>>(x2b, d_n1, n1b, stats + 128, g2, b2);

  // ---- stage 3: SparseInverseConv3d 64->32 (pairs swapped, sparse -> SKIP=true) ----
  hipMemsetAsync(tab, 0xFF, (size_t)N * 27 * 4, stream);
  build_table_kernel<<<dim3((P1 + 255) / 256, 27), 256, 0, stream>>>(
      p1_out, p1_in, P1, N, tab, nullptr, N);
  conv_mfma_kernel<2, 2, true><<<(N + 127) / 128, 256, 0, stream>>>(
      x2b, W3p, tab, N, n1b, nullptr, N, nullptr, out);
}

// Round 11
// 663.179 us; speedup vs baseline: 1.2729x; 1.2729x over previous
//
#include <hip/hip_runtime.h>
#include <hip/hip_bf16.h>

typedef __bf16 bf16x8 __attribute__((ext_vector_type(8)));
typedef float f32x4 __attribute__((ext_vector_type(4)));

__device__ __forceinline__ unsigned short f2bf(float x) {
  union { float f; unsigned int u; } v; v.f = x;
  unsigned int r = (v.u + 0x7FFFu + ((v.u >> 16) & 1u)) >> 16;
  return (unsigned short)r;
}
__device__ __forceinline__ float bf2f(unsigned short u) {
  union { unsigned int u; float f; } v; v.u = ((unsigned int)u) << 16;
  return v.f;
}

// feats [N][16] f32 -> [N+1][32] bf16 (upper 16 cols and row N stay zero via memset)
__global__ void cvt_feats_kernel(const float* __restrict__ f, unsigned short* __restrict__ fb, int n16) {
  int t = blockIdx.x * 256 + threadIdx.x;
  if (t >= n16) return;
  int i = t >> 4, j = t & 15;
  fb[(size_t)i * 32 + j] = f2bf(f[t]);
}

// Pack W[k][CI][CO] f32 into MFMA B-fragment order:
// Wp[(((k*NT+nt)*KK+kk)*64 + l)*8 + j] = bf16(W[k][kk*32 + (l>>4)*8 + j][nt*16 + (l&15)]), 0 if kg>=CI
__global__ void pack_w_kernel(const float* __restrict__ W, unsigned short* __restrict__ Wp,
                              int CI, int CO, int NT, int KK) {
  int t = blockIdx.x * 256 + threadIdx.x;
  int total = 27 * NT * KK * 512;
  if (t >= total) return;
  int j = t & 7, l = (t >> 3) & 63;
  int g = t >> 9;
  int kk = g % KK; g /= KK;
  int nt = g % NT; int k = g / NT;
  int kg = kk * 32 + ((l >> 4) * 8) + j;
  int c = nt * 16 + (l & 15);
  float v = (kg < CI) ? W[((size_t)k * CI + kg) * CO + c] : 0.0f;
  Wp[t] = f2bf(v);
}

// tab[k][o] = input index (scatter from pair lists; unique per (k,o) by construction)
__global__ void build_table_kernel(const int* __restrict__ pin, const int* __restrict__ pout,
                                   int P, int maxo, int* __restrict__ tab,
                                   const int* __restrict__ n_ptr, int n_cap) {
  int p = blockIdx.x * 256 + threadIdx.x;
  if (p >= P) return;
  int k = blockIdx.y;
  int n = n_cap;
  if (n_ptr) { int nv = n_ptr[0]; if (nv < n) n = nv; }
  size_t e = (size_t)k * P + p;
  int o = pout[e];
  if (o < n) tab[(size_t)k * maxo + o] = pin[e];
}

// Per-lane tab loads for this wave's two 16-row groups (predicated, no shfl).
#define LDTAB(KC_, T0, T1) do {                                                  \
    int _kc = (KC_) > 26 ? 26 : (KC_);                                           \
    T0 = ok0 ? tab[(size_t)_kc * maxo + row0] : -1;                              \
    T1 = ok1 ? tab[(size_t)_kc * maxo + row1] : -1;                              \
  } while (0)

// Gather A fragments into AB from tab values T0/T1; sets D (SKIP only).
#define ISSUE_A(AB, T0, T1, D) do {                                              \
    if (SKIP) D = (__ballot((T0) >= 0 || (T1) >= 0) != 0ull);                    \
    const unsigned short* _s0 = Xb + (size_t)((T0) < 0 ? zrow : (T0)) * ROWS + lg * 8; \
    _Pragma("unroll") for (int kk = 0; kk < KK; ++kk)                            \
      AB[0][kk] = *reinterpret_cast<const bf16x8*>(_s0 + kk * 32);               \
    const unsigned short* _s1 = Xb + (size_t)((T1) < 0 ? zrow : (T1)) * ROWS + lg * 8; \
    _Pragma("unroll") for (int kk = 0; kk < KK; ++kk)                            \
      AB[1][kk] = *reinterpret_cast<const bf16x8*>(_s1 + kk * 32);               \
  } while (0)

// Cooperative LDS staging of the 2 B sub-tiles (KB, KB+1) into PB.
#define STAGE_B2(KB, PB) do {                                                    \
    _Pragma("unroll") for (int _s = 0; _s < 2; ++_s) {                           \
      if ((KB) + _s <= 26) {                                                     \
        size_t _kb = (size_t)((KB) + _s) * (size_t)SZ;                           \
        _Pragma("unroll") for (int _j = 0; _j < PER; ++_j) {                     \
          int _c = w * PER + _j;                                                 \
          const unsigned char* _gp = WpB + _kb + (size_t)_c * 1024 + (size_t)l * 16; \
          __builtin_amdgcn_global_load_lds(                                      \
              (const __attribute__((address_space(1))) void*)_gp,                \
              (__attribute__((address_space(3))) void*)((PB) + _s * SZ + _c * 1024), 16, 0, 0); \
        }                                                                        \
      }                                                                          \
    }                                                                            \
  } while (0)

// ds_read B fragments from BCUR + MFMA on buffer AB (per-wave skip if empty).
#define STEP_CORE(BCUR, AB, D) do {                                              \
    if (!SKIP || (D)) {                                                          \
      _Pragma("unroll") for (int kk = 0; kk < KK; ++kk)                          \
        _Pragma("unroll") for (int nt = 0; nt < NT; ++nt) {                      \
          bf16x8 b = *reinterpret_cast<const bf16x8*>(&(BCUR)[(nt * KK + kk) * 1024 + l * 16]); \
          acc[0][nt] = __builtin_amdgcn_mfma_f32_16x16x32_bf16(AB[0][kk], b, acc[0][nt], 0, 0, 0); \
          acc[1][nt] = __builtin_amdgcn_mfma_f32_16x16x32_bf16(AB[1][kk], b, acc[1][nt], 0, 0, 0); \
        }                                                                        \
    }                                                                            \
  } while (0)

// Block = 4 waves x 32 rows, lockstep over k in GROUPS of 2 (14 barriers vs 27),
// B double-buffered in LDS (2 groups x 2 sub-tiles; 32KB for conv2 -> 4
// blocks/CU at launch_bounds(256,4), VGPR ~88 <= 128 so no spill). A per-wave
// ping-pong regs 2 steps ahead; tab 4 steps ahead.
template<int KK, int NT, bool SKIP>
__global__ __launch_bounds__(256, 4) void conv_mfma_kernel(
    const unsigned short* __restrict__ Xb, const unsigned short* __restrict__ Wp,
    const int* __restrict__ tab, int maxo, int zrow,
    const int* __restrict__ n_ptr, int n_cap,
    unsigned short* __restrict__ outb, float* __restrict__ outf) {
  const int CO = NT * 16;
  const int ROWS = KK * 32;           // shorts per X row
  constexpr int PER = (KK * NT) / 4;  // 1KB staging chunks per wave per sub-tile
  constexpr int SZ = KK * NT * 1024;  // bytes per B sub-tile

  __shared__ __align__(16) unsigned char Blds[2][2][SZ];

  int bid = blockIdx.x;
  { // bijective XCD-aware swizzle (m204)
    int nwg = gridDim.x;
    int q = nwg >> 3, r = nwg & 7;
    int xcd = bid & 7, orig = bid >> 3;
    bid = (xcd < r ? xcd * (q + 1) : r * (q + 1) + (xcd - r) * q) + orig;
  }

  int w = threadIdx.x >> 6, l = threadIdx.x & 63;
  int n_rows = n_cap;
  if (n_ptr) { int nv = n_ptr[0]; if (nv < n_rows) n_rows = nv; }
  if (bid * 128 >= n_rows) return;    // block-uniform exit (before any barrier)
  int lr = l & 15, lg = l >> 4;
  int wbase = bid * 128 + w * 32;
  int row0 = wbase + lr, row1 = wbase + 16 + lr;
  bool ok0 = row0 < n_rows, ok1 = row1 < n_rows;

  const unsigned char* WpB = (const unsigned char*)Wp;

  f32x4 acc[2][NT] = {};
  bf16x8 a0[2][KK], a1[2][KK];
  int tE0, tE1, tO0, tO1;
  bool dE = true, dO = true;

  // ---- prologue: stage group 0 (k=0,1); A(0),A(1); tab(2),tab(3) ----
  LDTAB(0, tE0, tE1);
  LDTAB(1, tO0, tO1);
  STAGE_B2(0, &Blds[0][0][0]);
  ISSUE_A(a0, tE0, tE1, dE);          // A(0), dE for step 0
  ISSUE_A(a1, tO0, tO1, dO);          // A(1), dO for step 1
  LDTAB(2, tE0, tE1);
  LDTAB(3, tO0, tO1);
  __syncthreads();                    // group 0 + A(0),A(1) + tabs complete

  // ---- 13 full groups (k=0..25), one barrier per group ----
#pragma unroll 1
  for (int g = 0; g < 13; ++g) {
    int kb = g * 2;
    unsigned char* bc = &Blds[g & 1][0][0];
    unsigned char* bn = &Blds[(g + 1) & 1][0][0];
    STAGE_B2(kb + 2, bn);             // stage next group (deep in vmem queue)
    STEP_CORE(bc + 0 * SZ, a0, dE); ISSUE_A(a0, tE0, tE1, dE); LDTAB(kb + 4, tE0, tE1);
    STEP_CORE(bc + 1 * SZ, a1, dO); ISSUE_A(a1, tO0, tO1, dO); LDTAB(kb + 5, tO0, tO1);
    __syncthreads();                  // next group staged; this buf free next iter
  }
  // ---- tail: k=26 (staged at g=12 into Blds[1][0]) ----
  STEP_CORE(&Blds[1][0][0], a0, dE);

#pragma unroll
  for (int mt = 0; mt < 2; ++mt) {
    int r0 = wbase + mt * 16 + lg * 4;
#pragma unroll
    for (int rr = 0; rr < 4; ++rr) {
      int row = r0 + rr;
      if (row < n_rows) {
#pragma unroll
        for (int nt = 0; nt < NT; ++nt) {
          size_t off = (size_t)row * CO + nt * 16 + lr;
          if (outf) outf[off] = acc[mt][nt][rr];
          else outb[off] = f2bf(acc[mt][nt][rr]);
        }
      }
    }
  }
}

__global__ void bn_stats_kernel(const unsigned short* __restrict__ xb,
                                const int* __restrict__ n_ptr, int n_cap,
                                float* __restrict__ stats) {
  int c = threadIdx.x & 63, q = threadIdx.x >> 6;
  int n = n_ptr[0]; if (n > n_cap) n = n_cap;
  float s = 0.f, ss = 0.f;
  for (int r = blockIdx.x * 4 + q; r < n; r += gridDim.x * 4) {
    float v = bf2f(xb[(size_t)r * 64 + c]);
    s += v; ss += v * v;
  }
  __shared__ float ls[8][64];
  ls[q][c] = s; ls[4 + q][c] = ss;
  __syncthreads();
  if (q == 0) {
    s = ls[0][c] + ls[1][c] + ls[2][c] + ls[3][c];
    ss = ls[4][c] + ls[5][c] + ls[6][c] + ls[7][c];
    atomicAdd(&stats[c], s);
    atomicAdd(&stats[64 + c], ss);
  }
}

__global__ void bn_apply_kernel(unsigned short* __restrict__ xb,
                                const int* __restrict__ n_ptr, int n_cap,
                                const float* __restrict__ stats,
                                const float* __restrict__ gamma, const float* __restrict__ beta) {
  int c = threadIdx.x & 63, q = threadIdx.x >> 6;
  int n = n_ptr[0]; if (n > n_cap) n = n_cap;
  float inv_n = 1.f / (float)n;
  float m = stats[c] * inv_n;
  float var = stats[64 + c] * inv_n - m * m;
  float sc = gamma[c] * rsqrtf(var + 1e-5f);
  float sh = beta[c] - m * sc;
  for (int r = blockIdx.x * 4 + q; r < n; r += gridDim.x * 4) {
    size_t off = (size_t)r * 64 + c;
    float v = bf2f(xb[off]) * sc + sh;
    xb[off] = f2bf(v > 0.f ? v : 0.f);
  }
}

extern "C" void kernel_launch(void* const* d_in, const int* in_sizes, int n_in,
                              void* d_out, int out_size, void* d_ws, size_t ws_size,
                              hipStream_t stream) {
  const float* feats  = (const float*)d_in[0];
  const float* W1     = (const float*)d_in[1];
  const float* g1     = (const float*)d_in[2];
  const float* b1     = (const float*)d_in[3];
  const float* W2     = (const float*)d_in[4];
  const float* g2     = (const float*)d_in[5];
  const float* b2     = (const float*)d_in[6];
  const float* W3     = (const float*)d_in[7];
  const int* p1_in    = (const int*)d_in[8];
  const int* p1_out   = (const int*)d_in[9];
  const int* p2_in    = (const int*)d_in[10];
  const int* p2_out   = (const int*)d_in[11];
  const int* d_n1     = (const int*)d_in[12];
  float* out = (float*)d_out;

  const int N  = in_sizes[0] / 16;     // 200000
  const int P1 = in_sizes[8] / 27;
  const int P2 = in_sizes[10] / 27;
  long KP1 = in_sizes[8];
  int n1b = (int)(KP1 < 980100 ? KP1 : 980100);   // n1 <= min(#pairs1, out-grid size)
  int maxo = n1b > N ? n1b : N;

  char* p = (char*)d_ws;
  auto alloc = [&](size_t bytes) -> char* {
    char* r = p; p += (bytes + 255) & ~(size_t)255; return r;
  };
  unsigned short* featsb = (unsigned short*)alloc((size_t)(N + 1) * 32 * 2);
  unsigned short* x1b    = (unsigned short*)alloc((size_t)(n1b + 1) * 64 * 2);
  unsigned short* x2b    = (unsigned short*)alloc((size_t)(n1b + 1) * 64 * 2);
  unsigned short* W1p    = (unsigned short*)alloc((size_t)27 * 4 * 1 * 512 * 2);
  unsigned short* W2p    = (unsigned short*)alloc((size_t)27 * 4 * 2 * 512 * 2);
  unsigned short* W3p    = (unsigned short*)alloc((size_t)27 * 2 * 2 * 512 * 2);
  int*   tab   = (int*)alloc((size_t)maxo * 27 * 4);
  float* stats = (float*)alloc(256 * 4);
  if ((size_t)(p - (char*)d_ws) > ws_size) return;  // workspace insufficient -> fail visibly

  // zero-init: padded feats buffer, the two zero-rows, BN stats
  hipMemsetAsync(featsb, 0, (size_t)(N + 1) * 32 * 2, stream);
  hipMemsetAsync(x1b + (size_t)n1b * 64, 0, 64 * 2, stream);
  hipMemsetAsync(x2b + (size_t)n1b * 64, 0, 64 * 2, stream);
  hipMemsetAsync(stats, 0, 256 * 4, stream);

  cvt_feats_kernel<<<(N * 16 + 255) / 256, 256, 0, stream>>>(feats, featsb, N * 16);
  pack_w_kernel<<<(27 * 4 * 1 * 512 + 255) / 256, 256, 0, stream>>>(W1, W1p, 16, 64, 4, 1);
  pack_w_kernel<<<(27 * 4 * 2 * 512 + 255) / 256, 256, 0, stream>>>(W2, W2p, 64, 64, 4, 2);
  pack_w_kernel<<<(27 * 2 * 2 * 512 + 255) / 256, 256, 0, stream>>>(W3, W3p, 64, 32, 2, 2);

  // ---- stage 1: SparseConv3d 16->64 (sparse tab -> SKIP=true) ----
  hipMemsetAsync(tab, 0xFF, (size_t)n1b * 27 * 4, stream);
  build_table_kernel<<<dim3((P1 + 255) / 256, 27), 256, 0, stream>>>(
      p1_in, p1_out, P1, n1b, tab, d_n1, n1b);
  conv_mfma_kernel<1, 4, true><<<(n1b + 127) / 128, 256, 0, stream>>>(
      featsb, W1p, tab, n1b, N, d_n1, n1b, x1b, nullptr);
  bn_stats_kernel<<<1024, 256, 0, stream>>>(x1b, d_n1, n1b, stats);
  bn_apply_kernel<<<2048, 256, 0, stream>>>(x1b, d_n1, n1b, stats, g1, b1);

  // ---- stage 2: SubMConv3d 64->64 (dense tab -> SKIP=false) ----
  hipMemsetAsync(tab, 0xFF, (size_t)n1b * 27 * 4, stream);
  build_table_kernel<<<dim3((P2 + 255) / 256, 27), 256, 0, stream>>>(
      p2_in, p2_out, P2, n1b, tab, d_n1, n1b);
  conv_mfma_kernel<2, 4, false><<<(n1b + 127) / 128, 256, 0, stream>>>(
      x1b, W2p, tab, n1b, n1b, d_n1, n1b, x2b, nullptr);
  bn_stats_kernel<<<1024, 256, 0, stream>>>(x2b, d_n1, n1b, stats + 128);
  bn_apply_kernel<<<2048, 256, 0, stream>>>(x2b, d_n1, n1b, stats + 128, g2, b2);

  // ---- stage 3: SparseInverseConv3d 64->32 (pairs swapped, sparse -> SKIP=true) ----
  hipMemsetAsync(tab, 0xFF, (size_t)N * 27 * 4, stream);
  build_table_kernel<<<dim3((P1 + 255) / 256, 27), 256, 0, stream>>>(
      p1_out, p1_in, P1, N, tab, nullptr, N);
  conv_mfma_kernel<2, 2, true><<<(N + 127) / 128, 256, 0, stream>>>(
      x2b, W3p, tab, N, n1b, nullptr, N, nullptr, out);
}